// Round 2
// baseline (66.266 us; speedup 1.0000x reference)
//
#include <hip/hip_runtime.h>
#include <hip/hip_fp16.h>

// out[b,l] = bias[l] + sum_i x_i W1[i,l] + sum_ij x_i x_j W2[i,j,l]
//          + sum_ijk x_i x_j x_k W3[i,j,k,l];  B=32768, D=K=32, fp32 in/out.
//
// Single f16-MFMA "feature GEMM": extend xt=[x_0..x_31, 1]. For each unordered
// pair (i<=j) over 33 indices (561 pairs), features f(pair,k)=xt_i*xt_j*x_k
// (k=0..31) contract with prebuilt coefficients G[pair][col=l][k]:
//   i<j<32 : W3[i,j,k,l]+W3[j,i,k,l]
//   i==j<32: W3[i,i,k,l]
//   j==32  : W2[i,k,l]   (order-2; p = x_i*1)
//   i==32  : W1[k,l]     (order-1; p = 1)
// FLOPs = 2*32768*561*1024 = 37.7 GF on v_mfma_f32_32x32x16_f16.
//
// Geometry (R1 fix: R0 grid covered 2x B -> OOB fault):
//   grid 256 blocks x 512 threads; block = 128 rows of X.
//   8 waves: group g = w>>1 (4-way pair split), gw = w&1 -> rows gw*64..+63
//   (2 MFMA row tiles of 32). Cross-group reduce via LDS at the end.

typedef __attribute__((ext_vector_type(8))) _Float16 f16x8;
typedef __attribute__((ext_vector_type(16))) float f32x16;

#define NPAIR 561
#define NB 4                // pairs per staged batch
#define PAIR_BYTES 2560     // 32 cols * 80 B (32 k f16 = 64B + 16B pad)
#define BATCH_BYTES (NB * PAIR_BYTES)
#define NBATCH 36           // ceil(141/4); uniform loop count for all groups

union H2V { __half2 h2[4]; f16x8 v; };

// ---------------- prep: build padded coefficient image in d_ws ----------------
__global__ void ntl_prep(const float* __restrict__ W1, const float* __restrict__ W2,
                         const float* __restrict__ W3, __half* __restrict__ Gimg) {
    int tid = blockIdx.x * 256 + threadIdx.x;
    if (tid >= NPAIR * 40 * 32) return;
    int col = tid & 31;          // output index l (fastest -> coalesced W reads)
    int k   = (tid >> 5) % 40;   // k slot (32..39 are pad)
    int m   = tid / (40 * 32);   // pair index
    int i = 0, rem = m;
    while (rem >= 33 - i) { rem -= 33 - i; ++i; }
    int j = i + rem;             // i <= j <= 32
    float v = 0.f;
    if (k < 32) {
        if (j < 32) {
            v = W3[((i * 32 + j) * 32 + k) * 32 + col];
            if (i != j) v += W3[((j * 32 + i) * 32 + k) * 32 + col];
        } else if (i < 32) {
            v = W2[(i * 32 + k) * 32 + col];
        } else {
            v = W1[k * 32 + col];
        }
    }
    Gimg[m * 1280 + col * 40 + k] = __float2half(v);
}

// ---------------- main fused kernel ----------------
__global__ __launch_bounds__(512, 2) void ntl_main(const float* __restrict__ X,
                                                   const float* __restrict__ bias,
                                                   const __half* __restrict__ Gimg,
                                                   float* __restrict__ out) {
    __shared__ __half xbuf[128 * 34];   // x tile f16, stride 34 (+1.0 at [32])
    __shared__ __align__(16) unsigned char gbuf[4][2][BATCH_BYTES]; // [group][dbuf] 81920 B

    const int tid = (int)threadIdx.x;
    const int w   = tid >> 6;
    const int l   = tid & 63;
    const int g   = w >> 1;      // pair group 0..3
    const int gw  = w & 1;       // row-wave within group
    const int h   = l >> 5;      // k-half of the lane within the wave
    const int lr  = l & 31;      // A row within tile / B col
    const long rowbase = (long)blockIdx.x * 128;

    // cooperative x -> LDS (f16)
    for (int idx = tid; idx < 128 * 32; idx += 512) {
        int r = idx >> 5, c = idx & 31;
        xbuf[r * 34 + c] = __float2half(X[(rowbase + r) * 32 + c]);
    }
    if (tid < 128) xbuf[tid * 34 + 32] = __float2half(1.0f);

    // per-lane A-side x slices, kept in registers the whole kernel.
    // MFMA 32x32x16 A layout: row = lane&31, k = 8*(lane>>5)+e (e=0..7).
    __half2 xk0[8], xk1[8];
#define LOADX(XK, TROW)                                                          \
    {                                                                            \
        const float* xp = X + (rowbase + gw * 64 + (TROW) + lr) * 32;            \
        float4 f0 = *(const float4*)(xp + 8 * h);                                \
        float4 f1 = *(const float4*)(xp + 8 * h + 4);                            \
        float4 f2 = *(const float4*)(xp + 16 + 8 * h);                           \
        float4 f3 = *(const float4*)(xp + 16 + 8 * h + 4);                       \
        XK[0] = __halves2half2(__float2half(f0.x), __float2half(f0.y));          \
        XK[1] = __halves2half2(__float2half(f0.z), __float2half(f0.w));          \
        XK[2] = __halves2half2(__float2half(f1.x), __float2half(f1.y));          \
        XK[3] = __halves2half2(__float2half(f1.z), __float2half(f1.w));          \
        XK[4] = __halves2half2(__float2half(f2.x), __float2half(f2.y));          \
        XK[5] = __halves2half2(__float2half(f2.z), __float2half(f2.w));          \
        XK[6] = __halves2half2(__float2half(f3.x), __float2half(f3.y));          \
        XK[7] = __halves2half2(__float2half(f3.z), __float2half(f3.w));          \
    }
    LOADX(xk0, 0)
    LOADX(xk1, 32)

    f32x16 acc0, acc1;
#pragma unroll
    for (int q = 0; q < 16; ++q) { acc0[q] = 0.f; acc1[q] = 0.f; }

    const int m0      = (g == 0) ? 0 : (141 + 140 * (g - 1));
    const int myPairs = (g == 0) ? 141 : 140;
    const int myNb    = (myPairs + NB - 1) / NB;   // 36 / 35

    // (i,j) cursor for this wave's first pair
    int pi = 0, rem = m0;
    while (rem >= 33 - pi) { rem -= 33 - pi; ++pi; }
    int pj = pi + rem;

    const unsigned char* gsrc = (const unsigned char*)Gimg;
    auto stage = [&](int bb, int dbuf) {
        int cnt = myPairs - bb * NB; if (cnt > NB) cnt = NB;
        if (cnt <= 0) return;
        int bytes = cnt * PAIR_BYTES;
        const unsigned char* src = gsrc + (size_t)(m0 + bb * NB) * PAIR_BYTES;
        unsigned char* dst = &gbuf[g][dbuf][0];
        // 2 row-waves of the group tile the batch: 1024 B per call per wave
        for (int ofs = gw * 1024; ofs < bytes; ofs += 2048) {
            __builtin_amdgcn_global_load_lds(
                (const __attribute__((address_space(1))) unsigned int*)(src + ofs + l * 16),
                (__attribute__((address_space(3))) unsigned int*)(dst + ofs),
                16, 0, 0);
        }
    };

    stage(0, 0);
    __syncthreads();   // drains vmcnt+lgkmcnt: xbuf and batch 0 ready

    for (int b = 0; b < NBATCH; ++b) {
        if (b + 1 < myNb) stage(b + 1, (b + 1) & 1);
        int cnt = myPairs - b * NB; if (cnt > NB) cnt = NB;
        const unsigned char* gb = &gbuf[g][b & 1][0];
        for (int s = 0; s < cnt; ++s) {
            const int xr0 = (gw * 64 + lr) * 34;
            const int xr1 = xr0 + 32 * 34;
            __half2 p20 = __half2half2(__hmul(xbuf[xr0 + pi], xbuf[xr0 + pj]));
            __half2 p21 = __half2half2(__hmul(xbuf[xr1 + pi], xbuf[xr1 + pj]));
            // B frags (shared by both row tiles): [col=lr][80B row], k-halves
            const f16x8 b0 = *(const f16x8*)(gb + s * PAIR_BYTES + lr * 80 + 16 * h);
            const f16x8 b1 = *(const f16x8*)(gb + s * PAIR_BYTES + lr * 80 + 32 + 16 * h);
            H2V a;
            a.h2[0] = __hmul2(p20, xk0[0]); a.h2[1] = __hmul2(p20, xk0[1]);
            a.h2[2] = __hmul2(p20, xk0[2]); a.h2[3] = __hmul2(p20, xk0[3]);
            acc0 = __builtin_amdgcn_mfma_f32_32x32x16_f16(a.v, b0, acc0, 0, 0, 0);
            a.h2[0] = __hmul2(p20, xk0[4]); a.h2[1] = __hmul2(p20, xk0[5]);
            a.h2[2] = __hmul2(p20, xk0[6]); a.h2[3] = __hmul2(p20, xk0[7]);
            acc0 = __builtin_amdgcn_mfma_f32_32x32x16_f16(a.v, b1, acc0, 0, 0, 0);
            a.h2[0] = __hmul2(p21, xk1[0]); a.h2[1] = __hmul2(p21, xk1[1]);
            a.h2[2] = __hmul2(p21, xk1[2]); a.h2[3] = __hmul2(p21, xk1[3]);
            acc1 = __builtin_amdgcn_mfma_f32_32x32x16_f16(a.v, b0, acc1, 0, 0, 0);
            a.h2[0] = __hmul2(p21, xk1[4]); a.h2[1] = __hmul2(p21, xk1[5]);
            a.h2[2] = __hmul2(p21, xk1[6]); a.h2[3] = __hmul2(p21, xk1[7]);
            acc1 = __builtin_amdgcn_mfma_f32_32x32x16_f16(a.v, b1, acc1, 0, 0, 0);
            ++pj; if (pj > 32) { ++pi; pj = pi; }
        }
        __syncthreads();
    }

    // cross-group reduce: groups 1..3 dump accs into LDS (aliases gbuf, safe
    // after the final barrier), group 0 adds + bias + stores.
    float* red = (float*)&gbuf[0][0][0];   // 3*2*2*16*64 = 12288 floats = 48 KB
    if (g >= 1) {
        int base = ((g - 1) * 2 + gw) * 2 * 16 * 64;
#pragma unroll
        for (int r = 0; r < 16; ++r) red[base + (0 * 16 + r) * 64 + l] = acc0[r];
#pragma unroll
        for (int r = 0; r < 16; ++r) red[base + (1 * 16 + r) * 64 + l] = acc1[r];
    }
    __syncthreads();
    if (g == 0) {
        float bcol = bias[lr];   // D col = lane&31
#pragma unroll
        for (int r = 0; r < 16; ++r) {
            // D layout: col = lane&31, row = (r&3) + 8*(r>>2) + 4*(lane>>5)
            int rowoff = (r & 3) + 8 * (r >> 2) + 4 * h;
            {
                float v = acc0[r] + bcol;
#pragma unroll
                for (int sg = 0; sg < 3; ++sg)
                    v += red[((sg * 2 + gw) * 2 + 0) * 16 * 64 + r * 64 + l];
                out[(rowbase + gw * 64 + rowoff) * 32 + lr] = v;
            }
            {
                float v = acc1[r] + bcol;
#pragma unroll
                for (int sg = 0; sg < 3; ++sg)
                    v += red[((sg * 2 + gw) * 2 + 1) * 16 * 64 + r * 64 + l];
                out[(rowbase + gw * 64 + 32 + rowoff) * 32 + lr] = v;
            }
        }
    }
}

extern "C" void kernel_launch(void* const* d_in, const int* in_sizes, int n_in,
                              void* d_out, int out_size, void* d_ws, size_t ws_size,
                              hipStream_t stream) {
    const float* X    = (const float*)d_in[0];
    const float* W1   = (const float*)d_in[1];
    const float* W2   = (const float*)d_in[2];
    const float* W3   = (const float*)d_in[3];
    const float* bias = (const float*)d_in[4];
    float* out = (float*)d_out;
    __half* Gimg = (__half*)d_ws;   // 561*2560 B = 1.44 MB

    int prep_threads = NPAIR * 40 * 32;
    ntl_prep<<<dim3((prep_threads + 255) / 256), dim3(256), 0, stream>>>(W1, W2, W3, Gimg);
    ntl_main<<<dim3(256), dim3(512), 0, stream>>>(X, bias, Gimg, out);
}

// Round 3
// 65.762 us; speedup vs baseline: 1.0077x; 1.0077x over previous
//
#include <hip/hip_runtime.h>
#include <hip/hip_fp16.h>

// out[b,l] = bias[l] + sum_i x_i W1[i,l] + sum_ij x_i x_j W2[i,j,l]
//          + sum_ijk x_i x_j x_k W3[i,j,k,l];  B=32768, D=K=32, fp32 in/out.
//
// Feature-GEMM over unordered pairs (i<=j) of xt=[x,1] (33 symbols, 561 pairs),
// f16 MFMA 32x32x16, fp32 accumulate. R3: barrier-free main loop — x rows live
// in registers (compile-time indexing via switch-fallthrough over j), B operand
// read straight from the L2-resident coefficient image (no LDS staging).

typedef __attribute__((ext_vector_type(8))) _Float16 f16x8;
typedef __attribute__((ext_vector_type(16))) float f32x16;

union AV   { __half2 h2[4];  f16x8 v;    };
union XROW { __half2 h2[16]; f16x8 v[4]; };

// Greedy-balanced run split: group g handles runs RUNPI[g][r] (r<NRUN[g]);
// run pi covers pairs (pi, j), j=pi..32. Loads: 141/140/140/140 pairs.
__device__ const int RUNPI[4][9] = {
    {0, 7, 8, 15, 16, 23, 24, 31, 32},
    {1, 6, 9, 14, 17, 22, 25, 30, 0},
    {2, 5, 10, 13, 18, 21, 26, 29, 0},
    {3, 4, 11, 12, 19, 20, 27, 28, 0}};
__device__ const int NRUN[4]  = {9, 8, 8, 8};
__device__ const int GBASE[5] = {0, 141, 281, 421, 561};

// ---------------- prep: per-group sequential coefficient streams ----------------
// Slot layout (2048 B): [khalf(2)][col(32)][k16(16)] f16. Slot order = group
// stream order (run-major, j ascending) so the main kernel reads sequentially.
__global__ void ntl_prep(const float* __restrict__ W1, const float* __restrict__ W2,
                         const float* __restrict__ W3, __half* __restrict__ Gimg) {
    int tid = blockIdx.x * 256 + threadIdx.x;
    if (tid >= 561 * 1024) return;
    int k    = tid & 31;
    int col  = (tid >> 5) & 31;
    int slot = tid >> 10;
    int g = 0;
    while (slot >= GBASE[g + 1]) ++g;
    int s = slot - GBASE[g];
    int r = 0, pi, len;
    for (;;) { pi = RUNPI[g][r]; len = 33 - pi; if (s < len) break; s -= len; ++r; }
    int j = pi + s;
    float v;
    if (j < 32) {
        v = W3[((pi * 32 + j) * 32 + k) * 32 + col];
        if (pi != j) v += W3[((j * 32 + pi) * 32 + k) * 32 + col];
    } else if (pi < 32) {
        v = W2[(pi * 32 + k) * 32 + col];
    } else {
        v = W1[k * 32 + col];
    }
    Gimg[slot * 1024 + (k >> 4) * 512 + col * 16 + (k & 15)] = __float2half(v);
}

// ---------------- main kernel ----------------
// grid 256 x 512 (8 waves). Block = 128 rows. Wave w: g=w>>1 (pair group),
// gw=w&1 -> rows gw*64..+63 (2 MFMA row tiles). LDS only for x staging +
// final cross-group reduction; main loop barrier-free.

#define XH(XR, J) (((J) & 1) ? __high2half((XR)[(J) >> 1]) : __low2half((XR)[(J) >> 1]))
#define MM(ACC, A, B) (ACC) = __builtin_amdgcn_mfma_f32_32x32x16_f16((A), (B), (ACC), 0, 0, 0)

#define PB(J)                                                                         \
    {                                                                                 \
        if ((J) < 32) { /* prefetch pair J+1 into opposite-parity regs */             \
            if (((J) & 1) == 0) { boa = *(const f16x8*)gp; bob = *(const f16x8*)(gp + 1024); } \
            else                { bea = *(const f16x8*)gp; beb = *(const f16x8*)(gp + 1024); } \
            gp += 2048;                                                               \
        }                                                                             \
        const f16x8 Ba = ((J) & 1) ? boa : bea;                                       \
        const f16x8 Bb = ((J) & 1) ? bob : beb;                                       \
        if ((J) == 32) { /* xt_j = 1: A-frag = yk directly */                         \
            MM(acc0, yk0[0].v, Ba); MM(acc0, yk0[1].v, Bb);                           \
            MM(acc1, yk1[0].v, Ba); MM(acc1, yk1[1].v, Bb);                           \
        } else {                                                                      \
            __half2 xj0 = __half2half2(XH(xa.h2, (J)));                               \
            __half2 xj1 = __half2half2(XH(xb.h2, (J)));                               \
            AV a0, a1;                                                                \
            a0.h2[0] = __hmul2(xj0, yk0[0].h2[0]); a0.h2[1] = __hmul2(xj0, yk0[0].h2[1]); \
            a0.h2[2] = __hmul2(xj0, yk0[0].h2[2]); a0.h2[3] = __hmul2(xj0, yk0[0].h2[3]); \
            MM(acc0, a0.v, Ba);                                                       \
            a1.h2[0] = __hmul2(xj0, yk0[1].h2[0]); a1.h2[1] = __hmul2(xj0, yk0[1].h2[1]); \
            a1.h2[2] = __hmul2(xj0, yk0[1].h2[2]); a1.h2[3] = __hmul2(xj0, yk0[1].h2[3]); \
            MM(acc0, a1.v, Bb);                                                       \
            a0.h2[0] = __hmul2(xj1, yk1[0].h2[0]); a0.h2[1] = __hmul2(xj1, yk1[0].h2[1]); \
            a0.h2[2] = __hmul2(xj1, yk1[0].h2[2]); a0.h2[3] = __hmul2(xj1, yk1[0].h2[3]); \
            MM(acc1, a0.v, Ba);                                                       \
            a1.h2[0] = __hmul2(xj1, yk1[1].h2[0]); a1.h2[1] = __hmul2(xj1, yk1[1].h2[1]); \
            a1.h2[2] = __hmul2(xj1, yk1[1].h2[2]); a1.h2[3] = __hmul2(xj1, yk1[1].h2[3]); \
            MM(acc1, a1.v, Bb);                                                       \
        }                                                                             \
    }

__global__ __launch_bounds__(512, 2) void ntl_main(const float* __restrict__ X,
                                                   const float* __restrict__ bias,
                                                   const __half* __restrict__ Gimg,
                                                   float* __restrict__ out) {
    __shared__ __half xbuf[128 * 40];   // row stride 40 halves (80 B, 16B-aligned)
    __shared__ float  red[12288];       // 48 KB cross-group reduction buffer

    const int tid = (int)threadIdx.x;
    const int w   = tid >> 6;
    const int l   = tid & 63;
    const int g   = w >> 1;      // pair group 0..3
    const int gw  = w & 1;       // row-wave within group
    const int h   = l >> 5;      // k-half
    const int lr  = l & 31;      // A row within tile / B col
    const long rowbase = (long)blockIdx.x * 128;

    // ---- prologue: x tile -> LDS (f16), then full rows -> registers ----
    {
        int r0 = tid >> 2, cb = (tid & 3) * 8;
        const float* xp = X + (rowbase + r0) * 32 + cb;
        float4 f0 = *(const float4*)xp;
        float4 f1 = *(const float4*)(xp + 4);
        __half2* dst = (__half2*)&xbuf[r0 * 40 + cb];
        dst[0] = __floats2half2_rn(f0.x, f0.y);
        dst[1] = __floats2half2_rn(f0.z, f0.w);
        dst[2] = __floats2half2_rn(f1.x, f1.y);
        dst[3] = __floats2half2_rn(f1.z, f1.w);
        if ((tid & 3) == 0) xbuf[r0 * 40 + 32] = __float2half(1.0f);
    }
    __syncthreads();

    XROW xa, xb;   // this lane's two x rows, halves 0..31
    {
        const f16x8* p0 = (const f16x8*)&xbuf[(gw * 64 + lr) * 40];
        const f16x8* p1 = (const f16x8*)&xbuf[(gw * 64 + 32 + lr) * 40];
        xa.v[0] = p0[0]; xa.v[1] = p0[1]; xa.v[2] = p0[2]; xa.v[3] = p0[3];
        xb.v[0] = p1[0]; xb.v[1] = p1[1]; xb.v[2] = p1[2]; xb.v[3] = p1[3];
    }

    // MFMA A-layout slices: xk[kh].h2[q] = x[16*kh + 8*h + 2q .. +1]
    AV xk0[2], xk1[2];
#pragma unroll
    for (int q = 0; q < 4; ++q) {
        xk0[0].h2[q] = h ? xa.h2[4 + q]  : xa.h2[q];
        xk0[1].h2[q] = h ? xa.h2[12 + q] : xa.h2[8 + q];
        xk1[0].h2[q] = h ? xb.h2[4 + q]  : xb.h2[q];
        xk1[1].h2[q] = h ? xb.h2[12 + q] : xb.h2[8 + q];
    }

    f32x16 acc0, acc1;
#pragma unroll
    for (int q = 0; q < 16; ++q) { acc0[q] = 0.f; acc1[q] = 0.f; }

    const char* gp = (const char*)Gimg + (size_t)GBASE[g] * 2048 + lr * 32 + h * 16;
    f16x8 bea{}, beb{}, boa{}, bob{};
    const int nr = NRUN[g];

    for (int rr = 0; rr < nr; ++rr) {
        const int pi = RUNPI[g][rr];
        __half2 hp0 = __half2half2(xbuf[(gw * 64 + lr) * 40 + pi]);
        __half2 hp1 = __half2half2(xbuf[(gw * 64 + 32 + lr) * 40 + pi]);
        AV yk0[2], yk1[2];   // run-invariant: x_pi * xk
#pragma unroll
        for (int q = 0; q < 4; ++q) {
            yk0[0].h2[q] = __hmul2(hp0, xk0[0].h2[q]);
            yk0[1].h2[q] = __hmul2(hp0, xk0[1].h2[q]);
            yk1[0].h2[q] = __hmul2(hp1, xk1[0].h2[q]);
            yk1[1].h2[q] = __hmul2(hp1, xk1[1].h2[q]);
        }
        // head loads for pair (pi,pi) into parity buffer pi&1
        if (pi & 1) { boa = *(const f16x8*)gp; bob = *(const f16x8*)(gp + 1024); }
        else        { bea = *(const f16x8*)gp; beb = *(const f16x8*)(gp + 1024); }
        gp += 2048;

        switch (pi) {
            case 0:  PB(0)
            case 1:  PB(1)
            case 2:  PB(2)
            case 3:  PB(3)
            case 4:  PB(4)
            case 5:  PB(5)
            case 6:  PB(6)
            case 7:  PB(7)
            case 8:  PB(8)
            case 9:  PB(9)
            case 10: PB(10)
            case 11: PB(11)
            case 12: PB(12)
            case 13: PB(13)
            case 14: PB(14)
            case 15: PB(15)
            case 16: PB(16)
            case 17: PB(17)
            case 18: PB(18)
            case 19: PB(19)
            case 20: PB(20)
            case 21: PB(21)
            case 22: PB(22)
            case 23: PB(23)
            case 24: PB(24)
            case 25: PB(25)
            case 26: PB(26)
            case 27: PB(27)
            case 28: PB(28)
            case 29: PB(29)
            case 30: PB(30)
            case 31: PB(31)
            case 32: PB(32)
        }
    }

    // ---- cross-group reduce: groups 1..3 dump, group 0 adds + bias + stores ----
    if (g >= 1) {
        int base = ((g - 1) * 2 + gw) * 2 * 16 * 64;
#pragma unroll
        for (int r = 0; r < 16; ++r) red[base + (0 * 16 + r) * 64 + l] = acc0[r];
#pragma unroll
        for (int r = 0; r < 16; ++r) red[base + (1 * 16 + r) * 64 + l] = acc1[r];
    }
    __syncthreads();
    if (g == 0) {
        float bcol = bias[lr];
#pragma unroll
        for (int r = 0; r < 16; ++r) {
            int rowoff = (r & 3) + 8 * (r >> 2) + 4 * h;   // D layout (verified R2)
            {
                float v = acc0[r] + bcol;
#pragma unroll
                for (int sg = 0; sg < 3; ++sg)
                    v += red[((sg * 2 + gw) * 2 + 0) * 16 * 64 + r * 64 + l];
                out[(rowbase + gw * 64 + rowoff) * 32 + lr] = v;
            }
            {
                float v = acc1[r] + bcol;
#pragma unroll
                for (int sg = 0; sg < 3; ++sg)
                    v += red[((sg * 2 + gw) * 2 + 1) * 16 * 64 + r * 64 + l];
                out[(rowbase + gw * 64 + 32 + rowoff) * 32 + lr] = v;
            }
        }
    }
}

extern "C" void kernel_launch(void* const* d_in, const int* in_sizes, int n_in,
                              void* d_out, int out_size, void* d_ws, size_t ws_size,
                              hipStream_t stream) {
    const float* X    = (const float*)d_in[0];
    const float* W1   = (const float*)d_in[1];
    const float* W2   = (const float*)d_in[2];
    const float* W3   = (const float*)d_in[3];
    const float* bias = (const float*)d_in[4];
    float* out  = (float*)d_out;
    __half* Gimg = (__half*)d_ws;   // 561 * 2048 B = 1.15 MB

    int prep_threads = 561 * 1024;
    ntl_prep<<<dim3((prep_threads + 255) / 256), dim3(256), 0, stream>>>(W1, W2, W3, Gimg);
    ntl_main<<<dim3(256), dim3(512), 0, stream>>>(X, bias, Gimg, out);
}